// Round 6
// baseline (14711.810 us; speedup 1.0000x reference)
//
#include <hip/hip_runtime.h>

typedef __attribute__((ext_vector_type(8))) short bh8;
typedef __attribute__((ext_vector_type(4))) float f4;
typedef __attribute__((ext_vector_type(4))) _Float16 hf4;

#define DEVINL __device__ __forceinline__

DEVINL float bf2f(unsigned short u){ unsigned x=((unsigned)u)<<16; return __builtin_bit_cast(float,x); }
DEVINL unsigned short f2bf(float f){ unsigned u=__builtin_bit_cast(unsigned,f); return (unsigned short)((u + 0x7fffu + ((u>>16)&1u))>>16); }
DEVINL float sigm(float x){ return 1.f/(1.f+__expf(-x)); }
DEVINL float tanh_f(float x){ float e=__expf(-2.f*fabsf(x)); float t=(1.f-e)/(1.f+e); return x<0.f?-t:t; }

// agent-scope cache-bypassing 16B read of h (2 x b64 relaxed atomic loads)
DEVINL bh8 load_h16(const unsigned short* p){
  const unsigned long long* q = (const unsigned long long*)p;
  unsigned long long lo = __hip_atomic_load(q,     __ATOMIC_RELAXED, __HIP_MEMORY_SCOPE_AGENT);
  unsigned long long hi = __hip_atomic_load(q + 1, __ATOMIC_RELAXED, __HIP_MEMORY_SCOPE_AGENT);
  union { unsigned long long v[2]; bh8 b; } u; u.v[0] = lo; u.v[1] = hi; return u.b;
}

// ---------------- f32 -> split bf16 (separate hi/lo arrays) ----------------
__global__ void cvt_split_sep(const float* __restrict__ in, unsigned short* __restrict__ oh,
                              unsigned short* __restrict__ ol, int n){
  int i = blockIdx.x*256 + threadIdx.x;
  if (i < n){
    float v = in[i];
    unsigned short h = f2bf(v);
    oh[i] = h;
    ol[i] = f2bf(v - bf2f(h));
  }
}

// ---------------- f32 [R][K] -> bf16 [R][2K] = [hi | lo] ----------------
template<int LOGK>
__global__ void cvt_split_pair(const float* __restrict__ in, unsigned short* __restrict__ out, int n){
  int i = blockIdx.x*256 + threadIdx.x;
  if (i < n){
    const int K = 1 << LOGK;
    int r = i >> LOGK, k = i & (K-1);
    float v = in[i];
    unsigned short h = f2bf(v);
    out[((size_t)r << (LOGK+1)) + k]     = h;
    out[((size_t)r << (LOGK+1)) + K + k] = f2bf(v - bf2f(h));
  }
}

// ---------------- fallback: zero output (signals ws_size problem distinctly) ----------------
__global__ void zero_out(float* __restrict__ o, int n){
  int i = blockIdx.x*256 + threadIdx.x;
  if (i < n) o[i] = 0.f;
}

// ---------------- encoder: conf-mask + relu(x@W^T+b) -> bf16 [16384][512] = [hi|lo] ----------------
__global__ __launch_bounds__(256) void enc_kernel(const float* __restrict__ feat,
    const float* __restrict__ W, const float* __restrict__ b, unsigned short* __restrict__ enc){
  __shared__ __align__(16) float x[52];
  int row = blockIdx.x; int tid = threadIdx.x;
  if (tid < 25){
    const float* fp = feat + (size_t)row*75 + tid*3;
    float m = fp[2] > 0.1f ? 1.f : 0.f;
    x[tid*2]   = fp[0]*m;
    x[tid*2+1] = fp[1]*m;
  }
  __syncthreads();
  const float* wr = W + tid*50;
  float s = b[tid];
  #pragma unroll
  for (int k=0;k<50;++k) s = fmaf(wr[k], x[k], s);
  s = fmaxf(s, 0.f);
  unsigned short h = f2bf(s);
  enc[(size_t)row*512 + tid]       = h;
  enc[(size_t)row*512 + 256 + tid] = f2bf(s - bf2f(h));
}

// ---------------- split xg GEMM ----------------
// A: [16384][2*KW] = [A_hi|A_lo], W: [4096][2*KW] = [W_hi|W_lo].
// 3 passes: A_hi*W_hi + A_hi*W_lo + A_lo*W_hi  ->  xg[2][16384][2048] (+bias)
template<int LOGKW, bool XGF32>
__global__ __launch_bounds__(256) void gemm_xg(
    const unsigned short* __restrict__ A, const unsigned short* __restrict__ W,
    const float* __restrict__ bias, void* __restrict__ xg)
{
  const int KW = 1 << LOGKW;
  __shared__ __align__(16) unsigned short As[128*64];
  __shared__ __align__(16) unsigned short Bs[128*64];
  const int bm = blockIdx.x, bn = blockIdx.y;
  const int tid = threadIdx.x, l = tid & 63;
  const int wm = (tid>>6)>>1, wn = (tid>>6)&1;
  const int lr = l & 15, lq = (l>>4)*8;
  f4 acc[4][4] = {};
  for (int k0 = 0; k0 < 3*KW; k0 += 64){
    const int p  = k0 >> LOGKW;
    const int kk = k0 & (KW-1);
    const int acol = (p==2 ? KW : 0) + kk;
    const int wcol = (p==1 ? KW : 0) + kk;
    bh8 ra[4], rb[4];
    #pragma unroll
    for (int j=0;j<4;++j){
      int c = j*256 + tid;
      int row = c >> 3, kc = c & 7;
      ra[j] = *(const bh8*)(A + ((size_t)(bm*128+row)<<(LOGKW+1)) + acol + kc*8);
      rb[j] = *(const bh8*)(W + ((size_t)(bn*128+row)<<(LOGKW+1)) + wcol + kc*8);
    }
    __syncthreads();   // previous iteration's readers done
    #pragma unroll
    for (int j=0;j<4;++j){
      int c = j*256 + tid;
      *(bh8*)(As + (size_t)c*8) = ra[j];
      *(bh8*)(Bs + (size_t)c*8) = rb[j];
    }
    __syncthreads();   // LDS writes visible
    #pragma unroll
    for (int kkk=0; kkk<64; kkk+=32){
      bh8 af[4], bfv[4];
      #pragma unroll
      for (int i=0;i<4;++i) af[i]  = *(const bh8*)(As + (wm*64 + i*16 + lr)*64 + kkk + lq);
      #pragma unroll
      for (int j=0;j<4;++j) bfv[j] = *(const bh8*)(Bs + (wn*64 + j*16 + lr)*64 + kkk + lq);
      #pragma unroll
      for (int i=0;i<4;++i)
        #pragma unroll
        for (int j=0;j<4;++j)
          acc[i][j] = __builtin_amdgcn_mfma_f32_16x16x32_bf16(af[i], bfv[j], acc[i][j], 0,0,0);
    }
  }
  #pragma unroll
  for (int j=0;j<4;++j){
    int n = bn*128 + wn*64 + j*16 + lr;
    float bv = bias[n];
    size_t dbase = (size_t)(n>>11)*16384*2048 + (size_t)(n & 2047);
    #pragma unroll
    for (int i=0;i<4;++i){
      int rowb = bm*128 + wm*64 + i*16 + ((l>>4)<<2);
      #pragma unroll
      for (int r=0;r<4;++r){
        float v = acc[i][j][r] + bv;
        size_t off = dbase + (size_t)(rowb + r)*2048;
        if constexpr (XGF32) ((float*)xg)[off] = v;
        else ((_Float16*)xg)[off] = (_Float16)v;
      }
    }
  }
}

// ---------------- persistent bidirectional LSTM recurrence (split-W_hh, gate-specialized waves) ----------------
// grid = 32 WGs (dir = bid>>4, slice sl = bid&15 owns js [sl*32, sl*32+32)), block = 256 (4 waves; wave w = gate g)
// Each wave: acc[2 Mtiles][2 Ntiles] over K=512, two W components (hi,lo) summed in-register.
// Gate pre-acts -> LDS gbuf[4][32 j][36 pad b] f32 -> 256 combine threads (thread = (b, 4 js)).
// ring: [4 slots][2 dir][32 b][512 j] bf16 (single-precision h).
// MODE 0: store per-t h (hi|lo) into h1[16384][2048]. MODE 1: accumulate pool, write d_out (f32).
template<bool XGF32, int MODE>
__global__ __launch_bounds__(256,1) void lstm_rec(
    const unsigned short* __restrict__ whh_hi, // [2][2048][512] bf16
    const unsigned short* __restrict__ whh_lo, // [2][2048][512] bf16
    const void* __restrict__ xg_,              // [2][16384][2048] f32 or fp16
    const int* __restrict__ lengths,           // [32]
    unsigned short* __restrict__ ring,         // [4][2][32][512] bf16
    unsigned short* __restrict__ h1,           // [16384][2048] bf16 ([hi|lo])
    float* __restrict__ outp,                  // [32][1024] f32
    unsigned int* __restrict__ ctrs)           // [2]
{
  const int bid = blockIdx.x;
  const int d = bid >> 4, sl = bid & 15;
  const int tid = threadIdx.x, l = tid & 63, g = tid >> 6;   // wave = gate
  const int lr = l & 15, kq = (l >> 4) * 8;

  __shared__ __align__(16) float gbuf[4][32][36];

  // register-resident split W_hh fragments: [comp][ntile][ktile]
  bh8 bfr[2][2][16];
  #pragma unroll
  for (int c=0;c<2;++c){
    const unsigned short* wb = (c ? whh_lo : whh_hi) + (size_t)(d*2048 + g*512)*512;
    #pragma unroll
    for (int nt=0;nt<2;++nt){
      const unsigned short* wr = wb + (size_t)(sl*32 + nt*16 + lr)*512;
      #pragma unroll
      for (int kt=0;kt<16;++kt)
        bfr[c][nt][kt] = *(const bh8*)(wr + kt*32 + kq);
    }
  }

  // combine-thread identity: b = tid>>3 (0..31), jq = (tid&7)*4 -> js jq..jq+3 within slice
  const int cb = tid >> 3, jq = (tid & 7) * 4;
  const int jjc = sl*32 + jq;
  const int len_b = lengths[cb];
  float c_st[4] = {0,0,0,0}, h_st[4] = {0,0,0,0}, pacc[4] = {0,0,0,0};

  const float*    xf = (const float*)xg_;
  const _Float16* xh = (const _Float16*)xg_;

  // per-step xg fragment: xgv[g][ji] (vector loads of 4 consecutive js)
  f4 xgv[4];
  auto xg_base = [&](int s_)->size_t{
    int act = s_ < len_b;
    int t = d ? (act ? (len_b-1-s_) : 0) : s_;
    return ((size_t)d*16384 + (size_t)cb*512 + t)*2048 + jjc;
  };
  {
    size_t bse = xg_base(0);
    #pragma unroll
    for (int gg=0;gg<4;++gg){
      if (XGF32) xgv[gg] = *(const f4*)(xf + bse + gg*512);
      else { hf4 hv = *(const hf4*)(xh + bse + gg*512);
             f4 t; t[0]=(float)hv[0]; t[1]=(float)hv[1]; t[2]=(float)hv[2]; t[3]=(float)hv[3]; xgv[gg]=t; }
    }
  }

  for (int s=0; s<512; ++s){
    // 1. A-frags: h from ring slot s&3 (agent-scope bypass loads). af[m][kt], m = batch-16-tile.
    const unsigned short* hbase = ring + ((size_t)((s&3)*2 + d))*32*512;
    bh8 af[2][16];
    #pragma unroll
    for (int m=0;m<2;++m)
      #pragma unroll
      for (int kt=0;kt<16;++kt)
        af[m][kt] = load_h16(hbase + (size_t)(m*16 + lr)*512 + kt*32 + kq);

    // 2. MFMA: both W components into same acc
    f4 acc[2][2] = {};
    #pragma unroll
    for (int kt=0;kt<16;++kt)
      #pragma unroll
      for (int m=0;m<2;++m)
        #pragma unroll
        for (int nt=0;nt<2;++nt){
          acc[m][nt] = __builtin_amdgcn_mfma_f32_16x16x32_bf16(af[m][kt], bfr[0][nt][kt], acc[m][nt], 0,0,0);
          acc[m][nt] = __builtin_amdgcn_mfma_f32_16x16x32_bf16(af[m][kt], bfr[1][nt][kt], acc[m][nt], 0,0,0);
        }

    // 3. gate pre-acts -> LDS. D-frag: col(j) = lr, rows(batch) = (l>>4)*4 + r (+ m*16)
    #pragma unroll
    for (int m=0;m<2;++m)
      #pragma unroll
      for (int nt=0;nt<2;++nt)
        *(f4*)&gbuf[g][nt*16 + lr][m*16 + ((l>>4)<<2)] = acc[m][nt];
    __syncthreads();

    // 4. combine: gates + xg -> nonlinear -> state -> publish
    unsigned short hbh[4], hbl[4];
    {
      bool act = s < len_b;
      float gv[4][4];
      #pragma unroll
      for (int gg=0;gg<4;++gg)
        #pragma unroll
        for (int ji=0;ji<4;++ji)
          gv[gg][ji] = gbuf[gg][jq+ji][cb] + xgv[gg][ji];
      #pragma unroll
      for (int ji=0;ji<4;++ji){
        float iv = sigm(gv[0][ji]);
        float fv = sigm(gv[1][ji]);
        float gg2 = tanh_f(gv[2][ji]);
        float ov = sigm(gv[3][ji]);
        float cn = fv*c_st[ji] + iv*gg2;
        float hn = ov*tanh_f(cn);
        if (act){ c_st[ji] = cn; h_st[ji] = hn; if (MODE==1) pacc[ji] += hn; }
        hbh[ji] = f2bf(h_st[ji]);
        hbl[ji] = f2bf(h_st[ji] - bf2f(hbh[ji]));
      }
      if (MODE==0 && act){
        int t = d ? (len_b-1-s) : s;
        size_t rb = ((size_t)cb*512 + t)*2048 + (size_t)d*512 + jjc;
        unsigned long long ph = ((unsigned long long)hbh[0]) | ((unsigned long long)hbh[1]<<16)
                              | ((unsigned long long)hbh[2]<<32) | ((unsigned long long)hbh[3]<<48);
        unsigned long long pl = ((unsigned long long)hbl[0]) | ((unsigned long long)hbl[1]<<16)
                              | ((unsigned long long)hbl[2]<<32) | ((unsigned long long)hbl[3]<<48);
        *(unsigned long long*)(h1 + rb)        = ph;
        *(unsigned long long*)(h1 + rb + 1024) = pl;
      }
      // publish h (single bf16) to ring slot (s+1)&3
      unsigned long long pk = ((unsigned long long)hbh[0]) | ((unsigned long long)hbh[1]<<16)
                            | ((unsigned long long)hbh[2]<<32) | ((unsigned long long)hbh[3]<<48);
      unsigned long long* dst = (unsigned long long*)
          (ring + ((size_t)(((s+1)&3)*2 + d))*32*512 + (size_t)cb*512 + jjc);
      __hip_atomic_store(dst, pk, __ATOMIC_RELAXED, __HIP_MEMORY_SCOPE_AGENT);
    }

    // 5. prefetch next step's xg (overlaps fence/barrier)
    {
      size_t bse = xg_base((s+1) & 511);
      #pragma unroll
      for (int gg=0;gg<4;++gg){
        if (XGF32) xgv[gg] = *(const f4*)(xf + bse + gg*512);
        else { hf4 hv = *(const hf4*)(xh + bse + gg*512);
               f4 t; t[0]=(float)hv[0]; t[1]=(float)hv[1]; t[2]=(float)hv[2]; t[3]=(float)hv[3]; xgv[gg]=t; }
      }
    }

    // 6. drain h-stores to agent coherence point, then 16-WG spin barrier
    __builtin_amdgcn_fence(__ATOMIC_RELEASE, "agent");
    __syncthreads();
    if (tid == 0){
      __hip_atomic_fetch_add(&ctrs[d], 1u, __ATOMIC_RELAXED, __HIP_MEMORY_SCOPE_AGENT);
      unsigned tgt = 16u * (unsigned)(s+1);
      while (__hip_atomic_load(&ctrs[d], __ATOMIC_ACQUIRE, __HIP_MEMORY_SCOPE_AGENT) < tgt)
        __builtin_amdgcn_s_sleep(1);
    }
    __syncthreads();
  }

  if (MODE==1){
    #pragma unroll
    for (int ji=0;ji<4;++ji)
      outp[(size_t)cb*1024 + (size_t)d*512 + jjc + ji] = pacc[ji] / (float)len_b;
  }
}

extern "C" void kernel_launch(void* const* d_in, const int* in_sizes, int n_in,
                              void* d_out, int out_size, void* d_ws, size_t ws_size,
                              hipStream_t stream)
{
  (void)in_sizes; (void)n_in;
  const float* feat = (const float*)d_in[0];
  const int*   lens = (const int*)d_in[1];
  const float* encW = (const float*)d_in[2];
  const float* encB = (const float*)d_in[3];
  const float* wih0 = (const float*)d_in[4];
  const float* whh0 = (const float*)d_in[5];
  const float* bl0  = (const float*)d_in[6];
  const float* wih1 = (const float*)d_in[7];
  const float* whh1 = (const float*)d_in[8];
  const float* bl1  = (const float*)d_in[9];
  float* outp = (float*)d_out;
  char* ws = (char*)d_ws;

  size_t off = 0;
  auto alloc = [&](size_t bytes){ size_t o = off; off += (bytes + 255) & ~(size_t)255; return o; };
  size_t o_ctr    = alloc(256);
  size_t o_ring   = alloc((size_t)4*2*32*512*2);
  size_t o_whh0h  = alloc((size_t)2097152*2);
  size_t o_whh0l  = alloc((size_t)2097152*2);
  size_t o_whh1h  = alloc((size_t)2097152*2);
  size_t o_whh1l  = alloc((size_t)2097152*2);
  size_t o_wih0s  = alloc((size_t)4096*512*2);
  size_t o_wih1s  = alloc((size_t)4096*2048*2);
  size_t o_enc    = alloc((size_t)16384*512*2);
  size_t o_h1     = alloc((size_t)16384*2048*2);
  size_t base = off;
  size_t need_f32 = base + (size_t)2*16384*2048*4;
  size_t need_f16 = base + (size_t)2*16384*2048*2;
  bool xgf32 = ws_size >= need_f32;
  if (ws_size < need_f16){
    zero_out<<<dim3((out_size+255)/256), dim3(256), 0, stream>>>(outp, out_size);
    return;
  }
  size_t o_xg = alloc(xgf32 ? (size_t)2*16384*2048*4 : (size_t)2*16384*2048*2);

  unsigned int*   ctrp  = (unsigned int*)(ws + o_ctr);
  unsigned short* ringp = (unsigned short*)(ws + o_ring);
  unsigned short* whh0h = (unsigned short*)(ws + o_whh0h);
  unsigned short* whh0l = (unsigned short*)(ws + o_whh0l);
  unsigned short* whh1h = (unsigned short*)(ws + o_whh1h);
  unsigned short* whh1l = (unsigned short*)(ws + o_whh1l);
  unsigned short* wih0s = (unsigned short*)(ws + o_wih0s);
  unsigned short* wih1s = (unsigned short*)(ws + o_wih1s);
  unsigned short* encp  = (unsigned short*)(ws + o_enc);
  unsigned short* h1p   = (unsigned short*)(ws + o_h1);
  void*           xgp   = (void*)(ws + o_xg);

  cvt_split_pair<8> <<<dim3((1048576+255)/256), dim3(256), 0, stream>>>(wih0, wih0s, 1048576);
  cvt_split_pair<10><<<dim3((4194304+255)/256), dim3(256), 0, stream>>>(wih1, wih1s, 4194304);
  cvt_split_sep<<<dim3((2097152+255)/256), dim3(256), 0, stream>>>(whh0, whh0h, whh0l, 2097152);
  cvt_split_sep<<<dim3((2097152+255)/256), dim3(256), 0, stream>>>(whh1, whh1h, whh1l, 2097152);

  enc_kernel<<<dim3(16384), dim3(256), 0, stream>>>(feat, encW, encB, encp);

  if (xgf32) gemm_xg<8,true ><<<dim3(128,32), dim3(256), 0, stream>>>(encp, wih0s, bl0, xgp);
  else       gemm_xg<8,false><<<dim3(128,32), dim3(256), 0, stream>>>(encp, wih0s, bl0, xgp);

  // zero ctrs + ring slot 0 (both dirs)
  hipMemsetAsync(ws, 0, 256 + (size_t)2*32*512*2, stream);

  if (xgf32) lstm_rec<true ,0><<<dim3(32), dim3(256), 0, stream>>>(whh0h, whh0l, xgp, lens, ringp, h1p, outp, ctrp);
  else       lstm_rec<false,0><<<dim3(32), dim3(256), 0, stream>>>(whh0h, whh0l, xgp, lens, ringp, h1p, outp, ctrp);

  if (xgf32) gemm_xg<10,true ><<<dim3(128,32), dim3(256), 0, stream>>>(h1p, wih1s, bl1, xgp);
  else       gemm_xg<10,false><<<dim3(128,32), dim3(256), 0, stream>>>(h1p, wih1s, bl1, xgp);

  hipMemsetAsync(ws, 0, 256 + (size_t)2*32*512*2, stream);

  if (xgf32) lstm_rec<true ,1><<<dim3(32), dim3(256), 0, stream>>>(whh1h, whh1l, xgp, lens, ringp, h1p, outp, ctrp);
  else       lstm_rec<false,1><<<dim3(32), dim3(256), 0, stream>>>(whh1h, whh1l, xgp, lens, ringp, h1p, outp, ctrp);
}

// Round 7
// 11806.032 us; speedup vs baseline: 1.2461x; 1.2461x over previous
//
#include <hip/hip_runtime.h>

typedef __attribute__((ext_vector_type(8))) short bh8;
typedef __attribute__((ext_vector_type(4))) float f4;
typedef __attribute__((ext_vector_type(4))) _Float16 hf4;

#define DEVINL __device__ __forceinline__

DEVINL float bf2f(unsigned short u){ unsigned x=((unsigned)u)<<16; return __builtin_bit_cast(float,x); }
DEVINL unsigned short f2bf(float f){ unsigned u=__builtin_bit_cast(unsigned,f); return (unsigned short)((u + 0x7fffu + ((u>>16)&1u))>>16); }
DEVINL float sigm(float x){ return 1.f/(1.f+__expf(-x)); }
DEVINL float tanh_f(float x){ float e=__expf(-2.f*fabsf(x)); float t=(1.f-e)/(1.f+e); return x<0.f?-t:t; }

// agent-scope cache-bypassing 16B read of h (2 x b64 relaxed atomic loads)
DEVINL bh8 load_h16(const unsigned short* p){
  const unsigned long long* q = (const unsigned long long*)p;
  unsigned long long lo = __hip_atomic_load(q,     __ATOMIC_RELAXED, __HIP_MEMORY_SCOPE_AGENT);
  unsigned long long hi = __hip_atomic_load(q + 1, __ATOMIC_RELAXED, __HIP_MEMORY_SCOPE_AGENT);
  union { unsigned long long v[2]; bh8 b; } u; u.v[0] = lo; u.v[1] = hi; return u.b;
}

// ---------------- f32 -> split bf16 (separate hi/lo arrays) ----------------
__global__ void cvt_split_sep(const float* __restrict__ in, unsigned short* __restrict__ oh,
                              unsigned short* __restrict__ ol, int n){
  int i = blockIdx.x*256 + threadIdx.x;
  if (i < n){
    float v = in[i];
    unsigned short h = f2bf(v);
    oh[i] = h;
    ol[i] = f2bf(v - bf2f(h));
  }
}

// ---------------- f32 [R][K] -> bf16 [R][2K] = [hi | lo] ----------------
template<int LOGK>
__global__ void cvt_split_pair(const float* __restrict__ in, unsigned short* __restrict__ out, int n){
  int i = blockIdx.x*256 + threadIdx.x;
  if (i < n){
    const int K = 1 << LOGK;
    int r = i >> LOGK, k = i & (K-1);
    float v = in[i];
    unsigned short h = f2bf(v);
    out[((size_t)r << (LOGK+1)) + k]     = h;
    out[((size_t)r << (LOGK+1)) + K + k] = f2bf(v - bf2f(h));
  }
}

// ---------------- fallback: zero output (signals ws_size problem distinctly) ----------------
__global__ void zero_out(float* __restrict__ o, int n){
  int i = blockIdx.x*256 + threadIdx.x;
  if (i < n) o[i] = 0.f;
}

// ---------------- encoder: conf-mask + relu(x@W^T+b) -> bf16 [16384][512] = [hi|lo] ----------------
__global__ __launch_bounds__(256) void enc_kernel(const float* __restrict__ feat,
    const float* __restrict__ W, const float* __restrict__ b, unsigned short* __restrict__ enc){
  __shared__ __align__(16) float x[52];
  int row = blockIdx.x; int tid = threadIdx.x;
  if (tid < 25){
    const float* fp = feat + (size_t)row*75 + tid*3;
    float m = fp[2] > 0.1f ? 1.f : 0.f;
    x[tid*2]   = fp[0]*m;
    x[tid*2+1] = fp[1]*m;
  }
  __syncthreads();
  const float* wr = W + tid*50;
  float s = b[tid];
  #pragma unroll
  for (int k=0;k<50;++k) s = fmaf(wr[k], x[k], s);
  s = fmaxf(s, 0.f);
  unsigned short h = f2bf(s);
  enc[(size_t)row*512 + tid]       = h;
  enc[(size_t)row*512 + 256 + tid] = f2bf(s - bf2f(h));
}

// ---------------- split xg GEMM ----------------
// A: [16384][2*KW] = [A_hi|A_lo], W: [4096][2*KW] = [W_hi|W_lo].
// 3 passes: A_hi*W_hi + A_hi*W_lo + A_lo*W_hi  ->  xg[2][16384][2048] (+bias)
template<int LOGKW, bool XGF32>
__global__ __launch_bounds__(256) void gemm_xg(
    const unsigned short* __restrict__ A, const unsigned short* __restrict__ W,
    const float* __restrict__ bias, void* __restrict__ xg)
{
  const int KW = 1 << LOGKW;
  __shared__ __align__(16) unsigned short As[128*64];
  __shared__ __align__(16) unsigned short Bs[128*64];
  const int bm = blockIdx.x, bn = blockIdx.y;
  const int tid = threadIdx.x, l = tid & 63;
  const int wm = (tid>>6)>>1, wn = (tid>>6)&1;
  const int lr = l & 15, lq = (l>>4)*8;
  f4 acc[4][4] = {};
  for (int k0 = 0; k0 < 3*KW; k0 += 64){
    const int p  = k0 >> LOGKW;
    const int kk = k0 & (KW-1);
    const int acol = (p==2 ? KW : 0) + kk;
    const int wcol = (p==1 ? KW : 0) + kk;
    bh8 ra[4], rb[4];
    #pragma unroll
    for (int j=0;j<4;++j){
      int c = j*256 + tid;
      int row = c >> 3, kc = c & 7;
      ra[j] = *(const bh8*)(A + ((size_t)(bm*128+row)<<(LOGKW+1)) + acol + kc*8);
      rb[j] = *(const bh8*)(W + ((size_t)(bn*128+row)<<(LOGKW+1)) + wcol + kc*8);
    }
    __syncthreads();   // previous iteration's readers done
    #pragma unroll
    for (int j=0;j<4;++j){
      int c = j*256 + tid;
      *(bh8*)(As + (size_t)c*8) = ra[j];
      *(bh8*)(Bs + (size_t)c*8) = rb[j];
    }
    __syncthreads();   // LDS writes visible
    #pragma unroll
    for (int kkk=0; kkk<64; kkk+=32){
      bh8 af[4], bfv[4];
      #pragma unroll
      for (int i=0;i<4;++i) af[i]  = *(const bh8*)(As + (wm*64 + i*16 + lr)*64 + kkk + lq);
      #pragma unroll
      for (int j=0;j<4;++j) bfv[j] = *(const bh8*)(Bs + (wn*64 + j*16 + lr)*64 + kkk + lq);
      #pragma unroll
      for (int i=0;i<4;++i)
        #pragma unroll
        for (int j=0;j<4;++j)
          acc[i][j] = __builtin_amdgcn_mfma_f32_16x16x32_bf16(af[i], bfv[j], acc[i][j], 0,0,0);
    }
  }
  #pragma unroll
  for (int j=0;j<4;++j){
    int n = bn*128 + wn*64 + j*16 + lr;
    float bv = bias[n];
    size_t dbase = (size_t)(n>>11)*16384*2048 + (size_t)(n & 2047);
    #pragma unroll
    for (int i=0;i<4;++i){
      int rowb = bm*128 + wm*64 + i*16 + ((l>>4)<<2);
      #pragma unroll
      for (int r=0;r<4;++r){
        float v = acc[i][j][r] + bv;
        size_t off = dbase + (size_t)(rowb + r)*2048;
        if constexpr (XGF32) ((float*)xg)[off] = v;
        else ((_Float16*)xg)[off] = (_Float16)v;
      }
    }
  }
}

// ---------------- persistent bidirectional LSTM recurrence (split-W_hh, gate-specialized waves) ----------------
// grid = 32 WGs (dir = bid>>4, slice sl = bid&15), block = 256 (4 waves; wave w = gate g)
// Sync: NO fences, NO hot counter. All cross-WG data via agent-scope relaxed atomics (LLC-coherent).
// Per-step: publish h -> __syncthreads (drains vmcnt) -> wave0: flag[wg]=s+1; poll 16 flags -> __syncthreads.
template<bool XGF32, int MODE>
__global__ __launch_bounds__(256,1) void lstm_rec(
    const unsigned short* __restrict__ whh_hi, // [2][2048][512] bf16
    const unsigned short* __restrict__ whh_lo, // [2][2048][512] bf16
    const void* __restrict__ xg_,              // [2][16384][2048] f32 or fp16
    const int* __restrict__ lengths,           // [32]
    unsigned short* __restrict__ ring,         // [4][2][32][512] bf16
    unsigned short* __restrict__ h1,           // [16384][2048] bf16 ([hi|lo])
    float* __restrict__ outp,                  // [32][1024] f32
    unsigned int* __restrict__ flags)          // [2][16] padded x16 dwords (64B each)
{
  const int bid = blockIdx.x;
  const int d = bid >> 4, sl = bid & 15;
  const int tid = threadIdx.x, l = tid & 63, g = tid >> 6;   // wave = gate
  const int lr = l & 15, kq = (l >> 4) * 8;

  __shared__ __align__(16) float gbuf[4][32][36];

  // register-resident split W_hh fragments: [comp][ntile][ktile]
  bh8 bfr[2][2][16];
  #pragma unroll
  for (int c=0;c<2;++c){
    const unsigned short* wb = (c ? whh_lo : whh_hi) + (size_t)(d*2048 + g*512)*512;
    #pragma unroll
    for (int nt=0;nt<2;++nt){
      const unsigned short* wr = wb + (size_t)(sl*32 + nt*16 + lr)*512;
      #pragma unroll
      for (int kt=0;kt<16;++kt)
        bfr[c][nt][kt] = *(const bh8*)(wr + kt*32 + kq);
    }
  }

  // combine-thread identity: b = tid>>3 (0..31), jq = (tid&7)*4 -> js jq..jq+3 within slice
  const int cb = tid >> 3, jq = (tid & 7) * 4;
  const int jjc = sl*32 + jq;
  const int len_b = lengths[cb];
  float c_st[4] = {0,0,0,0}, h_st[4] = {0,0,0,0}, pacc[4] = {0,0,0,0};

  const float*    xf = (const float*)xg_;
  const _Float16* xh = (const _Float16*)xg_;

  // per-step xg fragment: xgv[g][ji] (vector loads of 4 consecutive js)
  f4 xgv[4];
  auto xg_base = [&](int s_)->size_t{
    int act = s_ < len_b;
    int t = d ? (act ? (len_b-1-s_) : 0) : s_;
    return ((size_t)d*16384 + (size_t)cb*512 + t)*2048 + jjc;
  };
  {
    size_t bse = xg_base(0);
    #pragma unroll
    for (int gg=0;gg<4;++gg){
      if (XGF32) xgv[gg] = *(const f4*)(xf + bse + gg*512);
      else { hf4 hv = *(const hf4*)(xh + bse + gg*512);
             f4 t; t[0]=(float)hv[0]; t[1]=(float)hv[1]; t[2]=(float)hv[2]; t[3]=(float)hv[3]; xgv[gg]=t; }
    }
  }

  unsigned int* const my_flag = flags + (size_t)(d*16 + sl)*16;
  const unsigned int* const dir_flags = flags + (size_t)d*16*16;

  for (int s=0; s<512; ++s){
    // 1. A-frags: h from ring slot s&3 (agent-scope bypass loads). af[m][kt], m = batch-16-tile.
    const unsigned short* hbase = ring + ((size_t)((s&3)*2 + d))*32*512;
    bh8 af[2][16];
    #pragma unroll
    for (int m=0;m<2;++m)
      #pragma unroll
      for (int kt=0;kt<16;++kt)
        af[m][kt] = load_h16(hbase + (size_t)(m*16 + lr)*512 + kt*32 + kq);

    // 2. MFMA: both W components into same acc
    f4 acc[2][2] = {};
    #pragma unroll
    for (int kt=0;kt<16;++kt)
      #pragma unroll
      for (int m=0;m<2;++m)
        #pragma unroll
        for (int nt=0;nt<2;++nt){
          acc[m][nt] = __builtin_amdgcn_mfma_f32_16x16x32_bf16(af[m][kt], bfr[0][nt][kt], acc[m][nt], 0,0,0);
          acc[m][nt] = __builtin_amdgcn_mfma_f32_16x16x32_bf16(af[m][kt], bfr[1][nt][kt], acc[m][nt], 0,0,0);
        }

    // 3. gate pre-acts -> LDS. D-frag: col(j) = lr, rows(batch) = (l>>4)*4 + r (+ m*16)
    #pragma unroll
    for (int m=0;m<2;++m)
      #pragma unroll
      for (int nt=0;nt<2;++nt)
        *(f4*)&gbuf[g][nt*16 + lr][m*16 + ((l>>4)<<2)] = acc[m][nt];
    __syncthreads();

    // 4. combine: gates + xg -> nonlinear -> state -> publish
    unsigned short hbh[4], hbl[4];
    {
      bool act = s < len_b;
      float gv[4][4];
      #pragma unroll
      for (int gg=0;gg<4;++gg)
        #pragma unroll
        for (int ji=0;ji<4;++ji)
          gv[gg][ji] = gbuf[gg][jq+ji][cb] + xgv[gg][ji];
      #pragma unroll
      for (int ji=0;ji<4;++ji){
        float iv = sigm(gv[0][ji]);
        float fv = sigm(gv[1][ji]);
        float gg2 = tanh_f(gv[2][ji]);
        float ov = sigm(gv[3][ji]);
        float cn = fv*c_st[ji] + iv*gg2;
        float hn = ov*tanh_f(cn);
        if (act){ c_st[ji] = cn; h_st[ji] = hn; if (MODE==1) pacc[ji] += hn; }
        hbh[ji] = f2bf(h_st[ji]);
        hbl[ji] = f2bf(h_st[ji] - bf2f(hbh[ji]));
      }
      if (MODE==0 && act){
        int t = d ? (len_b-1-s) : s;
        size_t rb = ((size_t)cb*512 + t)*2048 + (size_t)d*512 + jjc;
        unsigned long long ph = ((unsigned long long)hbh[0]) | ((unsigned long long)hbh[1]<<16)
                              | ((unsigned long long)hbh[2]<<32) | ((unsigned long long)hbh[3]<<48);
        unsigned long long pl = ((unsigned long long)hbl[0]) | ((unsigned long long)hbl[1]<<16)
                              | ((unsigned long long)hbl[2]<<32) | ((unsigned long long)hbl[3]<<48);
        *(unsigned long long*)(h1 + rb)        = ph;
        *(unsigned long long*)(h1 + rb + 1024) = pl;
      }
      // publish h (single bf16) to ring slot (s+1)&3
      unsigned long long pk = ((unsigned long long)hbh[0]) | ((unsigned long long)hbh[1]<<16)
                            | ((unsigned long long)hbh[2]<<32) | ((unsigned long long)hbh[3]<<48);
      unsigned long long* dst = (unsigned long long*)
          (ring + ((size_t)(((s+1)&3)*2 + d))*32*512 + (size_t)cb*512 + jjc);
      __hip_atomic_store(dst, pk, __ATOMIC_RELAXED, __HIP_MEMORY_SCOPE_AGENT);
    }

    // 5. prefetch next step's xg (overlaps store drain)
    {
      size_t bse = xg_base((s+1) & 511);
      #pragma unroll
      for (int gg=0;gg<4;++gg){
        if (XGF32) xgv[gg] = *(const f4*)(xf + bse + gg*512);
        else { hf4 hv = *(const hf4*)(xh + bse + gg*512);
               f4 t; t[0]=(float)hv[0]; t[1]=(float)hv[1]; t[2]=(float)hv[2]; t[3]=(float)hv[3]; xgv[gg]=t; }
      }
    }

    // 6. barrier: __syncthreads drains each wave's vmem (h-stores at LLC); wave0 signals+polls flags.
    __syncthreads();
    if (tid < 64){
      unsigned tgt = (unsigned)(s+1);
      if (tid == 0)
        __hip_atomic_store(my_flag, tgt, __ATOMIC_RELAXED, __HIP_MEMORY_SCOPE_AGENT);
      for (;;){
        unsigned v = __hip_atomic_load(dir_flags + (size_t)(tid & 15)*16,
                                       __ATOMIC_RELAXED, __HIP_MEMORY_SCOPE_AGENT);
        if (__all(v >= tgt)) break;
      }
    }
    __syncthreads();
    asm volatile("" ::: "memory");
  }

  if (MODE==1){
    #pragma unroll
    for (int ji=0;ji<4;++ji)
      outp[(size_t)cb*1024 + (size_t)d*512 + jjc + ji] = pacc[ji] / (float)len_b;
  }
}

extern "C" void kernel_launch(void* const* d_in, const int* in_sizes, int n_in,
                              void* d_out, int out_size, void* d_ws, size_t ws_size,
                              hipStream_t stream)
{
  (void)in_sizes; (void)n_in;
  const float* feat = (const float*)d_in[0];
  const int*   lens = (const int*)d_in[1];
  const float* encW = (const float*)d_in[2];
  const float* encB = (const float*)d_in[3];
  const float* wih0 = (const float*)d_in[4];
  const float* whh0 = (const float*)d_in[5];
  const float* bl0  = (const float*)d_in[6];
  const float* wih1 = (const float*)d_in[7];
  const float* whh1 = (const float*)d_in[8];
  const float* bl1  = (const float*)d_in[9];
  float* outp = (float*)d_out;
  char* ws = (char*)d_ws;

  size_t off = 0;
  auto alloc = [&](size_t bytes){ size_t o = off; off += (bytes + 255) & ~(size_t)255; return o; };
  size_t o_flag   = alloc(2048);                        // [2][16] flags, 64B-padded
  size_t o_ring   = alloc((size_t)4*2*32*512*2);        // ring: 4 slots x 2 dir x 32 x 512
  size_t o_whh0h  = alloc((size_t)2097152*2);
  size_t o_whh0l  = alloc((size_t)2097152*2);
  size_t o_whh1h  = alloc((size_t)2097152*2);
  size_t o_whh1l  = alloc((size_t)2097152*2);
  size_t o_wih0s  = alloc((size_t)4096*512*2);
  size_t o_wih1s  = alloc((size_t)4096*2048*2);
  size_t o_enc    = alloc((size_t)16384*512*2);
  size_t o_h1     = alloc((size_t)16384*2048*2);
  size_t base = off;
  size_t need_f32 = base + (size_t)2*16384*2048*4;
  size_t need_f16 = base + (size_t)2*16384*2048*2;
  bool xgf32 = ws_size >= need_f32;
  if (ws_size < need_f16){
    zero_out<<<dim3((out_size+255)/256), dim3(256), 0, stream>>>(outp, out_size);
    return;
  }
  size_t o_xg = alloc(xgf32 ? (size_t)2*16384*2048*4 : (size_t)2*16384*2048*2);

  unsigned int*   flagp = (unsigned int*)(ws + o_flag);
  unsigned short* ringp = (unsigned short*)(ws + o_ring);
  unsigned short* whh0h = (unsigned short*)(ws + o_whh0h);
  unsigned short* whh0l = (unsigned short*)(ws + o_whh0l);
  unsigned short* whh1h = (unsigned short*)(ws + o_whh1h);
  unsigned short* whh1l = (unsigned short*)(ws + o_whh1l);
  unsigned short* wih0s = (unsigned short*)(ws + o_wih0s);
  unsigned short* wih1s = (unsigned short*)(ws + o_wih1s);
  unsigned short* encp  = (unsigned short*)(ws + o_enc);
  unsigned short* h1p   = (unsigned short*)(ws + o_h1);
  void*           xgp   = (void*)(ws + o_xg);

  cvt_split_pair<8> <<<dim3((1048576+255)/256), dim3(256), 0, stream>>>(wih0, wih0s, 1048576);
  cvt_split_pair<10><<<dim3((4194304+255)/256), dim3(256), 0, stream>>>(wih1, wih1s, 4194304);
  cvt_split_sep<<<dim3((2097152+255)/256), dim3(256), 0, stream>>>(whh0, whh0h, whh0l, 2097152);
  cvt_split_sep<<<dim3((2097152+255)/256), dim3(256), 0, stream>>>(whh1, whh1h, whh1l, 2097152);

  enc_kernel<<<dim3(16384), dim3(256), 0, stream>>>(feat, encW, encB, encp);

  if (xgf32) gemm_xg<8,true ><<<dim3(128,32), dim3(256), 0, stream>>>(encp, wih0s, bl0, xgp);
  else       gemm_xg<8,false><<<dim3(128,32), dim3(256), 0, stream>>>(encp, wih0s, bl0, xgp);

  // zero flags + ring slot 0 (both dirs): flags 2048B at ws+0, ring slot0 = 64KB at ws+2048
  hipMemsetAsync(ws, 0, 2048 + (size_t)2*32*512*2, stream);

  if (xgf32) lstm_rec<true ,0><<<dim3(32), dim3(256), 0, stream>>>(whh0h, whh0l, xgp, lens, ringp, h1p, outp, flagp);
  else       lstm_rec<false,0><<<dim3(32), dim3(256), 0, stream>>>(whh0h, whh0l, xgp, lens, ringp, h1p, outp, flagp);

  if (xgf32) gemm_xg<10,true ><<<dim3(128,32), dim3(256), 0, stream>>>(h1p, wih1s, bl1, xgp);
  else       gemm_xg<10,false><<<dim3(128,32), dim3(256), 0, stream>>>(h1p, wih1s, bl1, xgp);

  hipMemsetAsync(ws, 0, 2048 + (size_t)2*32*512*2, stream);

  if (xgf32) lstm_rec<true ,1><<<dim3(32), dim3(256), 0, stream>>>(whh1h, whh1l, xgp, lens, ringp, h1p, outp, flagp);
  else       lstm_rec<false,1><<<dim3(32), dim3(256), 0, stream>>>(whh1h, whh1l, xgp, lens, ringp, h1p, outp, flagp);
}

// Round 8
// 8235.118 us; speedup vs baseline: 1.7865x; 1.4336x over previous
//
#include <hip/hip_runtime.h>

typedef __attribute__((ext_vector_type(8))) short bh8;
typedef __attribute__((ext_vector_type(4))) float f4;
typedef __attribute__((ext_vector_type(4))) _Float16 hf4;

#define DEVINL __device__ __forceinline__

DEVINL float bf2f(unsigned short u){ unsigned x=((unsigned)u)<<16; return __builtin_bit_cast(float,x); }
DEVINL unsigned short f2bf(float f){ unsigned u=__builtin_bit_cast(unsigned,f); return (unsigned short)((u + 0x7fffu + ((u>>16)&1u))>>16); }
DEVINL float sigm(float x){ return 1.f/(1.f+__expf(-x)); }
DEVINL float tanh_f(float x){ float e=__expf(-2.f*fabsf(x)); float t=(1.f-e)/(1.f+e); return x<0.f?-t:t; }

// agent-scope cache-bypassing 16B read of h (2 x b64 relaxed atomic loads)
DEVINL bh8 load_h16(const unsigned short* p){
  const unsigned long long* q = (const unsigned long long*)p;
  unsigned long long lo = __hip_atomic_load(q,     __ATOMIC_RELAXED, __HIP_MEMORY_SCOPE_AGENT);
  unsigned long long hi = __hip_atomic_load(q + 1, __ATOMIC_RELAXED, __HIP_MEMORY_SCOPE_AGENT);
  union { unsigned long long v[2]; bh8 b; } u; u.v[0] = lo; u.v[1] = hi; return u.b;
}

// ---------------- f32 -> split bf16 (separate hi/lo arrays) ----------------
__global__ void cvt_split_sep(const float* __restrict__ in, unsigned short* __restrict__ oh,
                              unsigned short* __restrict__ ol, int n){
  int i = blockIdx.x*256 + threadIdx.x;
  if (i < n){
    float v = in[i];
    unsigned short h = f2bf(v);
    oh[i] = h;
    ol[i] = f2bf(v - bf2f(h));
  }
}

// ---------------- f32 [R][K] -> bf16 [R][2K] = [hi | lo] ----------------
template<int LOGK>
__global__ void cvt_split_pair(const float* __restrict__ in, unsigned short* __restrict__ out, int n){
  int i = blockIdx.x*256 + threadIdx.x;
  if (i < n){
    const int K = 1 << LOGK;
    int r = i >> LOGK, k = i & (K-1);
    float v = in[i];
    unsigned short h = f2bf(v);
    out[((size_t)r << (LOGK+1)) + k]     = h;
    out[((size_t)r << (LOGK+1)) + K + k] = f2bf(v - bf2f(h));
  }
}

// ---------------- fallback: zero output (signals ws_size problem distinctly) ----------------
__global__ void zero_out(float* __restrict__ o, int n){
  int i = blockIdx.x*256 + threadIdx.x;
  if (i < n) o[i] = 0.f;
}

// ---------------- encoder: conf-mask + relu(x@W^T+b) -> bf16 [16384][512] = [hi|lo] ----------------
__global__ __launch_bounds__(256) void enc_kernel(const float* __restrict__ feat,
    const float* __restrict__ W, const float* __restrict__ b, unsigned short* __restrict__ enc){
  __shared__ __align__(16) float x[52];
  int row = blockIdx.x; int tid = threadIdx.x;
  if (tid < 25){
    const float* fp = feat + (size_t)row*75 + tid*3;
    float m = fp[2] > 0.1f ? 1.f : 0.f;
    x[tid*2]   = fp[0]*m;
    x[tid*2+1] = fp[1]*m;
  }
  __syncthreads();
  const float* wr = W + tid*50;
  float s = b[tid];
  #pragma unroll
  for (int k=0;k<50;++k) s = fmaf(wr[k], x[k], s);
  s = fmaxf(s, 0.f);
  unsigned short h = f2bf(s);
  enc[(size_t)row*512 + tid]       = h;
  enc[(size_t)row*512 + 256 + tid] = f2bf(s - bf2f(h));
}

// ---------------- split xg GEMM ----------------
// A: [16384][2*KW] = [A_hi|A_lo], W: [4096][2*KW] = [W_hi|W_lo].
// 3 passes: A_hi*W_hi + A_hi*W_lo + A_lo*W_hi  ->  xg[2][16384][2048] (+bias)
template<int LOGKW, bool XGF32>
__global__ __launch_bounds__(256) void gemm_xg(
    const unsigned short* __restrict__ A, const unsigned short* __restrict__ W,
    const float* __restrict__ bias, void* __restrict__ xg)
{
  const int KW = 1 << LOGKW;
  __shared__ __align__(16) unsigned short As[128*64];
  __shared__ __align__(16) unsigned short Bs[128*64];
  const int bm = blockIdx.x, bn = blockIdx.y;
  const int tid = threadIdx.x, l = tid & 63;
  const int wm = (tid>>6)>>1, wn = (tid>>6)&1;
  const int lr = l & 15, lq = (l>>4)*8;
  f4 acc[4][4] = {};
  for (int k0 = 0; k0 < 3*KW; k0 += 64){
    const int p  = k0 >> LOGKW;
    const int kk = k0 & (KW-1);
    const int acol = (p==2 ? KW : 0) + kk;
    const int wcol = (p==1 ? KW : 0) + kk;
    bh8 ra[4], rb[4];
    #pragma unroll
    for (int j=0;j<4;++j){
      int c = j*256 + tid;
      int row = c >> 3, kc = c & 7;
      ra[j] = *(const bh8*)(A + ((size_t)(bm*128+row)<<(LOGKW+1)) + acol + kc*8);
      rb[j] = *(const bh8*)(W + ((size_t)(bn*128+row)<<(LOGKW+1)) + wcol + kc*8);
    }
    __syncthreads();   // previous iteration's readers done
    #pragma unroll
    for (int j=0;j<4;++j){
      int c = j*256 + tid;
      *(bh8*)(As + (size_t)c*8) = ra[j];
      *(bh8*)(Bs + (size_t)c*8) = rb[j];
    }
    __syncthreads();   // LDS writes visible
    #pragma unroll
    for (int kkk=0; kkk<64; kkk+=32){
      bh8 af[4], bfv[4];
      #pragma unroll
      for (int i=0;i<4;++i) af[i]  = *(const bh8*)(As + (wm*64 + i*16 + lr)*64 + kkk + lq);
      #pragma unroll
      for (int j=0;j<4;++j) bfv[j] = *(const bh8*)(Bs + (wn*64 + j*16 + lr)*64 + kkk + lq);
      #pragma unroll
      for (int i=0;i<4;++i)
        #pragma unroll
        for (int j=0;j<4;++j)
          acc[i][j] = __builtin_amdgcn_mfma_f32_16x16x32_bf16(af[i], bfv[j], acc[i][j], 0,0,0);
    }
  }
  #pragma unroll
  for (int j=0;j<4;++j){
    int n = bn*128 + wn*64 + j*16 + lr;
    float bv = bias[n];
    size_t dbase = (size_t)(n>>11)*16384*2048 + (size_t)(n & 2047);
    #pragma unroll
    for (int i=0;i<4;++i){
      int rowb = bm*128 + wm*64 + i*16 + ((l>>4)<<2);
      #pragma unroll
      for (int r=0;r<4;++r){
        float v = acc[i][j][r] + bv;
        size_t off = dbase + (size_t)(rowb + r)*2048;
        if constexpr (XGF32) ((float*)xg)[off] = v;
        else ((_Float16*)xg)[off] = (_Float16)v;
      }
    }
  }
}

// ---------------- persistent bidirectional LSTM recurrence (split-W_hh, gate-specialized waves) ----------------
// grid = 32 WGs (dir = bid>>4, slice sl = bid&15), block = 256 (4 waves; wave w = gate g)
// Ring stores h in MFMA-FRAGMENT-MAJOR layout per (slot, dir):
//   element index = f*512 + l*8 + e, where f = m*16+kt, and h[b][j] maps via
//   b = (f>>4)*16 + (l&15), j = (f&15)*32 + (l>>4)*8 + e.
// Reader: lane l loads 16B at f*512 + l*8 -> fully coalesced (64 lanes x 16B = 1KB contiguous).
// Publisher: thread (cb,jq)'s 4 j-values = one b64 store at f=(cb>>4)*16+sl, l=(cb&15)|((jq>>3)<<4), e=jq&7.
template<bool XGF32, int MODE>
__global__ __launch_bounds__(256,1) void lstm_rec(
    const unsigned short* __restrict__ whh_hi, // [2][2048][512] bf16
    const unsigned short* __restrict__ whh_lo, // [2][2048][512] bf16
    const void* __restrict__ xg_,              // [2][16384][2048] f32 or fp16
    const int* __restrict__ lengths,           // [32]
    unsigned short* __restrict__ ring,         // [4][2][32*512] bf16, fragment-major
    unsigned short* __restrict__ h1,           // [16384][2048] bf16 ([hi|lo])
    float* __restrict__ outp,                  // [32][1024] f32
    unsigned int* __restrict__ flags)          // [2][16] padded x16 dwords (64B each)
{
  const int bid = blockIdx.x;
  const int d = bid >> 4, sl = bid & 15;
  const int tid = threadIdx.x, l = tid & 63, g = tid >> 6;   // wave = gate
  const int lr = l & 15, kq = (l >> 4) * 8;

  __shared__ __align__(16) float gbuf[4][32][36];

  // register-resident split W_hh fragments: [comp][ntile][ktile]
  bh8 bfr[2][2][16];
  #pragma unroll
  for (int c=0;c<2;++c){
    const unsigned short* wb = (c ? whh_lo : whh_hi) + (size_t)(d*2048 + g*512)*512;
    #pragma unroll
    for (int nt=0;nt<2;++nt){
      const unsigned short* wr = wb + (size_t)(sl*32 + nt*16 + lr)*512;
      #pragma unroll
      for (int kt=0;kt<16;++kt)
        bfr[c][nt][kt] = *(const bh8*)(wr + kt*32 + kq);
    }
  }

  // combine-thread identity: b = tid>>3 (0..31), jq = (tid&7)*4 -> js jq..jq+3 within slice
  const int cb = tid >> 3, jq = (tid & 7) * 4;
  const int jjc = sl*32 + jq;
  const int len_b = lengths[cb];
  float c_st[4] = {0,0,0,0}, h_st[4] = {0,0,0,0}, pacc[4] = {0,0,0,0};

  // publish slot coordinates (fragment-major)
  const int fpub = ((cb>>4)<<4) | sl;
  const int lpub = (cb&15) | (((jq>>3)&3)<<4);
  const int epub = jq & 7;
  const size_t pub_off = (size_t)fpub*512 + (size_t)lpub*8 + epub;

  const float*    xf = (const float*)xg_;
  const _Float16* xh = (const _Float16*)xg_;

  // per-step xg fragment: xgv[g][ji] (vector loads of 4 consecutive js)
  f4 xgv[4];
  auto xg_base = [&](int s_)->size_t{
    int act = s_ < len_b;
    int t = d ? (act ? (len_b-1-s_) : 0) : s_;
    return ((size_t)d*16384 + (size_t)cb*512 + t)*2048 + jjc;
  };
  {
    size_t bse = xg_base(0);
    #pragma unroll
    for (int gg=0;gg<4;++gg){
      if (XGF32) xgv[gg] = *(const f4*)(xf + bse + gg*512);
      else { hf4 hv = *(const hf4*)(xh + bse + gg*512);
             f4 t; t[0]=(float)hv[0]; t[1]=(float)hv[1]; t[2]=(float)hv[2]; t[3]=(float)hv[3]; xgv[gg]=t; }
    }
  }

  unsigned int* const my_flag = flags + (size_t)(d*16 + sl)*16;
  const unsigned int* const dir_flags = flags + (size_t)d*16*16;

  for (int s=0; s<512; ++s){
    // 1. A-frags from ring slot s&3 (fragment-major, coalesced agent-scope bypass loads)
    const unsigned short* hbase = ring + ((size_t)((s&3)*2 + d))*32*512;
    bh8 af[2][16];
    #pragma unroll
    for (int m=0;m<2;++m)
      #pragma unroll
      for (int kt=0;kt<16;++kt)
        af[m][kt] = load_h16(hbase + (size_t)(m*16+kt)*512 + l*8);

    // 2. MFMA: both W components into same acc
    f4 acc[2][2] = {};
    #pragma unroll
    for (int kt=0;kt<16;++kt)
      #pragma unroll
      for (int m=0;m<2;++m)
        #pragma unroll
        for (int nt=0;nt<2;++nt){
          acc[m][nt] = __builtin_amdgcn_mfma_f32_16x16x32_bf16(af[m][kt], bfr[0][nt][kt], acc[m][nt], 0,0,0);
          acc[m][nt] = __builtin_amdgcn_mfma_f32_16x16x32_bf16(af[m][kt], bfr[1][nt][kt], acc[m][nt], 0,0,0);
        }

    // 3. gate pre-acts -> LDS. D-frag: col(j) = lr, rows(batch) = (l>>4)*4 + r (+ m*16)
    #pragma unroll
    for (int m=0;m<2;++m)
      #pragma unroll
      for (int nt=0;nt<2;++nt)
        *(f4*)&gbuf[g][nt*16 + lr][m*16 + ((l>>4)<<2)] = acc[m][nt];
    __syncthreads();

    // 4. combine: gates + xg -> nonlinear -> state -> publish
    unsigned short hbh[4], hbl[4];
    {
      bool act = s < len_b;
      float gv[4][4];
      #pragma unroll
      for (int gg=0;gg<4;++gg)
        #pragma unroll
        for (int ji=0;ji<4;++ji)
          gv[gg][ji] = gbuf[gg][jq+ji][cb] + xgv[gg][ji];
      #pragma unroll
      for (int ji=0;ji<4;++ji){
        float iv = sigm(gv[0][ji]);
        float fv = sigm(gv[1][ji]);
        float gg2 = tanh_f(gv[2][ji]);
        float ov = sigm(gv[3][ji]);
        float cn = fv*c_st[ji] + iv*gg2;
        float hn = ov*tanh_f(cn);
        if (act){ c_st[ji] = cn; h_st[ji] = hn; if (MODE==1) pacc[ji] += hn; }
        hbh[ji] = f2bf(h_st[ji]);
        hbl[ji] = f2bf(h_st[ji] - bf2f(hbh[ji]));
      }
      if (MODE==0 && act){
        int t = d ? (len_b-1-s) : s;
        size_t rb = ((size_t)cb*512 + t)*2048 + (size_t)d*512 + jjc;
        unsigned long long ph = ((unsigned long long)hbh[0]) | ((unsigned long long)hbh[1]<<16)
                              | ((unsigned long long)hbh[2]<<32) | ((unsigned long long)hbh[3]<<48);
        unsigned long long pl = ((unsigned long long)hbl[0]) | ((unsigned long long)hbl[1]<<16)
                              | ((unsigned long long)hbl[2]<<32) | ((unsigned long long)hbl[3]<<48);
        *(unsigned long long*)(h1 + rb)        = ph;
        *(unsigned long long*)(h1 + rb + 1024) = pl;
      }
      // publish h (single bf16) to ring slot (s+1)&3, fragment-major
      unsigned long long pk = ((unsigned long long)hbh[0]) | ((unsigned long long)hbh[1]<<16)
                            | ((unsigned long long)hbh[2]<<32) | ((unsigned long long)hbh[3]<<48);
      unsigned long long* dst = (unsigned long long*)
          (ring + ((size_t)(((s+1)&3)*2 + d))*32*512 + pub_off);
      __hip_atomic_store(dst, pk, __ATOMIC_RELAXED, __HIP_MEMORY_SCOPE_AGENT);
    }

    // 5. prefetch next step's xg (overlaps store drain)
    {
      size_t bse = xg_base((s+1) & 511);
      #pragma unroll
      for (int gg=0;gg<4;++gg){
        if (XGF32) xgv[gg] = *(const f4*)(xf + bse + gg*512);
        else { hf4 hv = *(const hf4*)(xh + bse + gg*512);
               f4 t; t[0]=(float)hv[0]; t[1]=(float)hv[1]; t[2]=(float)hv[2]; t[3]=(float)hv[3]; xgv[gg]=t; }
      }
    }

    // 6. barrier: __syncthreads drains each wave's vmem (h-stores at LLC); wave0 signals+polls flags.
    __syncthreads();
    if (tid < 64){
      unsigned tgt = (unsigned)(s+1);
      if (tid == 0)
        __hip_atomic_store(my_flag, tgt, __ATOMIC_RELAXED, __HIP_MEMORY_SCOPE_AGENT);
      for (;;){
        unsigned v = __hip_atomic_load(dir_flags + (size_t)(tid & 15)*16,
                                       __ATOMIC_RELAXED, __HIP_MEMORY_SCOPE_AGENT);
        if (__all(v >= tgt)) break;
      }
    }
    __syncthreads();
    asm volatile("" ::: "memory");
  }

  if (MODE==1){
    #pragma unroll
    for (int ji=0;ji<4;++ji)
      outp[(size_t)cb*1024 + (size_t)d*512 + jjc + ji] = pacc[ji] / (float)len_b;
  }
}

extern "C" void kernel_launch(void* const* d_in, const int* in_sizes, int n_in,
                              void* d_out, int out_size, void* d_ws, size_t ws_size,
                              hipStream_t stream)
{
  (void)in_sizes; (void)n_in;
  const float* feat = (const float*)d_in[0];
  const int*   lens = (const int*)d_in[1];
  const float* encW = (const float*)d_in[2];
  const float* encB = (const float*)d_in[3];
  const float* wih0 = (const float*)d_in[4];
  const float* whh0 = (const float*)d_in[5];
  const float* bl0  = (const float*)d_in[6];
  const float* wih1 = (const float*)d_in[7];
  const float* whh1 = (const float*)d_in[8];
  const float* bl1  = (const float*)d_in[9];
  float* outp = (float*)d_out;
  char* ws = (char*)d_ws;

  size_t off = 0;
  auto alloc = [&](size_t bytes){ size_t o = off; off += (bytes + 255) & ~(size_t)255; return o; };
  size_t o_flag   = alloc(2048);                        // [2][16] flags, 64B-padded
  size_t o_ring   = alloc((size_t)4*2*32*512*2);        // ring: 4 slots x 2 dir x 32*512 (fragment-major)
  size_t o_whh0h  = alloc((size_t)2097152*2);
  size_t o_whh0l  = alloc((size_t)2097152*2);
  size_t o_whh1h  = alloc((size_t)2097152*2);
  size_t o_whh1l  = alloc((size_t)2097152*2);
  size_t o_wih0s  = alloc((size_t)4096*512*2);
  size_t o_wih1s  = alloc((size_t)4096*2048*2);
  size_t o_enc    = alloc((size_t)16384*512*2);
  size_t o_h1     = alloc((size_t)16384*2048*2);
  size_t base = off;
  size_t need_f32 = base + (size_t)2*16384*2048*4;
  size_t need_f16 = base + (size_t)2*16384*2048*2;
  bool xgf32 = ws_size >= need_f32;
  if (ws_size < need_f16){
    zero_out<<<dim3((out_size+255)/256), dim3(256), 0, stream>>>(outp, out_size);
    return;
  }
  size_t o_xg = alloc(xgf32 ? (size_t)2*16384*2048*4 : (size_t)2*16384*2048*2);

  unsigned int*   flagp = (unsigned int*)(ws + o_flag);
  unsigned short* ringp = (unsigned short*)(ws + o_ring);
  unsigned short* whh0h = (unsigned short*)(ws + o_whh0h);
  unsigned short* whh0l = (unsigned short*)(ws + o_whh0l);
  unsigned short* whh1h = (unsigned short*)(ws + o_whh1h);
  unsigned short* whh1l = (unsigned short*)(ws + o_whh1l);
  unsigned short* wih0s = (unsigned short*)(ws + o_wih0s);
  unsigned short* wih1s = (unsigned short*)(ws + o_wih1s);
  unsigned short* encp  = (unsigned short*)(ws + o_enc);
  unsigned short* h1p   = (unsigned short*)(ws + o_h1);
  void*           xgp   = (void*)(ws + o_xg);

  cvt_split_pair<8> <<<dim3((1048576+255)/256), dim3(256), 0, stream>>>(wih0, wih0s, 1048576);
  cvt_split_pair<10><<<dim3((4194304+255)/256), dim3(256), 0, stream>>>(wih1, wih1s, 4194304);
  cvt_split_sep<<<dim3((2097152+255)/256), dim3(256), 0, stream>>>(whh0, whh0h, whh0l, 2097152);
  cvt_split_sep<<<dim3((2097152+255)/256), dim3(256), 0, stream>>>(whh1, whh1h, whh1l, 2097152);

  enc_kernel<<<dim3(16384), dim3(256), 0, stream>>>(feat, encW, encB, encp);

  if (xgf32) gemm_xg<8,true ><<<dim3(128,32), dim3(256), 0, stream>>>(encp, wih0s, bl0, xgp);
  else       gemm_xg<8,false><<<dim3(128,32), dim3(256), 0, stream>>>(encp, wih0s, bl0, xgp);

  // zero flags + ring slot 0 (both dirs): flags 2048B at ws+0, ring slot0 = 64KB at ws+2048
  hipMemsetAsync(ws, 0, 2048 + (size_t)2*32*512*2, stream);

  if (xgf32) lstm_rec<true ,0><<<dim3(32), dim3(256), 0, stream>>>(whh0h, whh0l, xgp, lens, ringp, h1p, outp, flagp);
  else       lstm_rec<false,0><<<dim3(32), dim3(256), 0, stream>>>(whh0h, whh0l, xgp, lens, ringp, h1p, outp, flagp);

  if (xgf32) gemm_xg<10,true ><<<dim3(128,32), dim3(256), 0, stream>>>(h1p, wih1s, bl1, xgp);
  else       gemm_xg<10,false><<<dim3(128,32), dim3(256), 0, stream>>>(h1p, wih1s, bl1, xgp);

  hipMemsetAsync(ws, 0, 2048 + (size_t)2*32*512*2, stream);

  if (xgf32) lstm_rec<true ,1><<<dim3(32), dim3(256), 0, stream>>>(whh1h, whh1l, xgp, lens, ringp, h1p, outp, flagp);
  else       lstm_rec<false,1><<<dim3(32), dim3(256), 0, stream>>>(whh1h, whh1l, xgp, lens, ringp, h1p, outp, flagp);
}